// Round 1
// baseline (4559.765 us; speedup 1.0000x reference)
//
#include <hip/hip_runtime.h>
#include <math.h>

#define TILE 64
#define KT 16

__device__ __forceinline__ float phi_act(float t) {
    // silu(t) + 1
    return t / (1.0f + __expf(-t)) + 1.0f;
}

// C[M,N] = A[M,K] @ W[N,K]^T (+ bias), optional phi((.)*scale) activation.
// mode 0: acc + bias
// mode 1: phi((acc + bias) * scale)   (bias may be null -> 0)
__device__ __forceinline__ void gemm_body(
    const float* __restrict__ A, const float* __restrict__ W,
    const float* __restrict__ bias, float* __restrict__ C,
    int M, int N, int K, int mode, float scale)
{
    __shared__ float As[KT][TILE + 4];
    __shared__ float Ws[KT][TILE + 4];
    const int tid = threadIdx.x;
    const int bm = blockIdx.y, bn = blockIdx.x;
    const int lrow = tid >> 2;          // 0..63
    const int kc4  = (tid & 3) << 2;    // 0,4,8,12
    const float* Ap = A + (size_t)(bm * TILE + lrow) * K + kc4;
    const float* Wp = W + (size_t)(bn * TILE + lrow) * K + kc4;
    const int tx = tid & 15, ty = tid >> 4;   // 16x16 thread grid, 4x4 each
    float acc[4][4] = {};

    for (int k0 = 0; k0 < K; k0 += KT) {
        float4 a4 = *(const float4*)(Ap + k0);
        float4 w4 = *(const float4*)(Wp + k0);
        __syncthreads();
        As[kc4 + 0][lrow] = a4.x; As[kc4 + 1][lrow] = a4.y;
        As[kc4 + 2][lrow] = a4.z; As[kc4 + 3][lrow] = a4.w;
        Ws[kc4 + 0][lrow] = w4.x; Ws[kc4 + 1][lrow] = w4.y;
        Ws[kc4 + 2][lrow] = w4.z; Ws[kc4 + 3][lrow] = w4.w;
        __syncthreads();
        #pragma unroll
        for (int kk = 0; kk < KT; kk++) {
            float4 av = *(const float4*)&As[kk][ty << 2];
            float4 wv = *(const float4*)&Ws[kk][tx << 2];
            acc[0][0] += av.x * wv.x; acc[0][1] += av.x * wv.y; acc[0][2] += av.x * wv.z; acc[0][3] += av.x * wv.w;
            acc[1][0] += av.y * wv.x; acc[1][1] += av.y * wv.y; acc[1][2] += av.y * wv.z; acc[1][3] += av.y * wv.w;
            acc[2][0] += av.z * wv.x; acc[2][1] += av.z * wv.y; acc[2][2] += av.z * wv.z; acc[2][3] += av.z * wv.w;
            acc[3][0] += av.w * wv.x; acc[3][1] += av.w * wv.y; acc[3][2] += av.w * wv.z; acc[3][3] += av.w * wv.w;
        }
    }

    const int cm = bm * TILE + (ty << 2);
    const int cn = bn * TILE + (tx << 2);
    float4 b4 = make_float4(0.f, 0.f, 0.f, 0.f);
    if (bias) b4 = *(const float4*)(bias + cn);
    #pragma unroll
    for (int i = 0; i < 4; i++) {
        float4 r;
        r.x = acc[i][0] + b4.x;
        r.y = acc[i][1] + b4.y;
        r.z = acc[i][2] + b4.z;
        r.w = acc[i][3] + b4.w;
        if (mode == 1) {
            r.x = phi_act(r.x * scale);
            r.y = phi_act(r.y * scale);
            r.z = phi_act(r.z * scale);
            r.w = phi_act(r.w * scale);
        }
        *(float4*)&C[(size_t)(cm + i) * N + cn] = r;
    }
}

// Fused q/k/v projection: blockIdx.z selects which output.
__global__ __launch_bounds__(256) void qkv_gemm(
    const float* __restrict__ x,
    const float* __restrict__ Wq, const float* __restrict__ bq,
    const float* __restrict__ Wk,
    const float* __restrict__ Wv, const float* __restrict__ bv,
    float* __restrict__ phiq, float* __restrict__ phik, float* __restrict__ vbuf,
    int M, int N, int K, float scale)
{
    int z = blockIdx.z;
    if (z == 0)      gemm_body(x, Wq, bq,      phiq, M, N, K, 1, scale);
    else if (z == 1) gemm_body(x, Wk, nullptr, phik, M, N, K, 1, scale);
    else             gemm_body(x, Wv, bv,      vbuf, M, N, K, 0, 1.0f);
}

__global__ __launch_bounds__(256) void out_gemm(
    const float* __restrict__ A, const float* __restrict__ W,
    const float* __restrict__ bias, float* __restrict__ C,
    int M, int N, int K)
{
    gemm_body(A, W, bias, C, M, N, K, 0, 1.0f);
}

// kv[bh][d][e] = sum_t phiK[b, t, h*64+d] * V[b, t, h*64+e]
__global__ __launch_bounds__(256) void kv_kernel(
    const float* __restrict__ phiK, const float* __restrict__ V,
    float* __restrict__ KV, int Ttot, int D)
{
    const int bh = blockIdx.x;
    const int b = bh >> 4, h = bh & 15;
    __shared__ float pk[32][64];
    __shared__ float vv[32][64];
    const int tid = threadIdx.x;
    const int tx = tid & 15, ty = tid >> 4;
    const int e0 = tx << 2, d0 = ty << 2;
    float acc[4][4] = {};
    const size_t base = (size_t)b * Ttot * D + h * 64;

    for (int t0 = 0; t0 < Ttot; t0 += 32) {
        __syncthreads();
        #pragma unroll
        for (int u = 0; u < 2; u++) {
            int f = tid * 2 + u;           // 0..511
            int r = f >> 4;                // 0..31
            int c4 = (f & 15) << 2;        // 0..60
            size_t g = base + (size_t)(t0 + r) * D + c4;
            *(float4*)&pk[r][c4] = *(const float4*)(phiK + g);
            *(float4*)&vv[r][c4] = *(const float4*)(V + g);
        }
        __syncthreads();
        #pragma unroll
        for (int tt = 0; tt < 32; tt++) {
            float4 a = *(const float4*)&pk[tt][d0];
            float4 w = *(const float4*)&vv[tt][e0];
            acc[0][0] += a.x * w.x; acc[0][1] += a.x * w.y; acc[0][2] += a.x * w.z; acc[0][3] += a.x * w.w;
            acc[1][0] += a.y * w.x; acc[1][1] += a.y * w.y; acc[1][2] += a.y * w.z; acc[1][3] += a.y * w.w;
            acc[2][0] += a.z * w.x; acc[2][1] += a.z * w.y; acc[2][2] += a.z * w.z; acc[2][3] += a.z * w.w;
            acc[3][0] += a.w * w.x; acc[3][1] += a.w * w.y; acc[3][2] += a.w * w.z; acc[3][3] += a.w * w.w;
        }
    }
    float* outp = KV + (size_t)bh * 4096;
    #pragma unroll
    for (int i = 0; i < 4; i++) {
        float4 r = make_float4(acc[i][0], acc[i][1], acc[i][2], acc[i][3]);
        *(float4*)&outp[(d0 + i) * 64 + e0] = r;
    }
}

// Oattn[b, t, h*64+e] = sum_d phiQ[b, t, h*64+d] * kv[bh][d][e]
__global__ __launch_bounds__(256) void av_kernel(
    const float* __restrict__ phiQ, const float* __restrict__ KV,
    float* __restrict__ Oattn, int Ttot, int D)
{
    const int bh = blockIdx.y;
    const int b = bh >> 4, h = bh & 15;
    const int t0 = blockIdx.x * 64;
    __shared__ float kvs[64][64];
    __shared__ float pqT[64][64 + 4];
    const int tid = threadIdx.x;
    const int tx = tid & 15, ty = tid >> 4;

    const float* kvp = KV + (size_t)bh * 4096;
    #pragma unroll
    for (int u = 0; u < 4; u++) {
        int f = tid + u * 256;             // 0..1023 (float4 index)
        int r = f >> 4;
        int c4 = (f & 15) << 2;
        *(float4*)&kvs[r][c4] = *(const float4*)(kvp + f * 4);
        float4 g = *(const float4*)(phiQ + (size_t)(b * Ttot + t0 + r) * D + h * 64 + c4);
        pqT[c4 + 0][r] = g.x; pqT[c4 + 1][r] = g.y;
        pqT[c4 + 2][r] = g.z; pqT[c4 + 3][r] = g.w;
    }
    __syncthreads();

    const int e0 = tx << 2, tl0 = ty << 2;
    float acc[4][4] = {};
    #pragma unroll 8
    for (int d = 0; d < 64; d++) {
        float4 a = *(const float4*)&pqT[d][tl0];
        float4 w = *(const float4*)&kvs[d][e0];
        acc[0][0] += a.x * w.x; acc[0][1] += a.x * w.y; acc[0][2] += a.x * w.z; acc[0][3] += a.x * w.w;
        acc[1][0] += a.y * w.x; acc[1][1] += a.y * w.y; acc[1][2] += a.y * w.z; acc[1][3] += a.y * w.w;
        acc[2][0] += a.z * w.x; acc[2][1] += a.z * w.y; acc[2][2] += a.z * w.z; acc[2][3] += a.z * w.w;
        acc[3][0] += a.w * w.x; acc[3][1] += a.w * w.y; acc[3][2] += a.w * w.z; acc[3][3] += a.w * w.w;
    }
    #pragma unroll
    for (int i = 0; i < 4; i++) {
        float4 r = make_float4(acc[i][0], acc[i][1], acc[i][2], acc[i][3]);
        *(float4*)&Oattn[(size_t)(b * Ttot + t0 + tl0 + i) * D + h * 64 + e0] = r;
    }
}

extern "C" void kernel_launch(void* const* d_in, const int* in_sizes, int n_in,
                              void* d_out, int out_size, void* d_ws, size_t ws_size,
                              hipStream_t stream) {
    const float* x  = (const float*)d_in[0];
    const float* Wq = (const float*)d_in[1];
    const float* bq = (const float*)d_in[2];
    const float* Wk = (const float*)d_in[3];
    const float* Wv = (const float*)d_in[4];
    const float* bv = (const float*)d_in[5];
    const float* Wo = (const float*)d_in[6];
    const float* bo = (const float*)d_in[7];
    float* out = (float*)d_out;

    const int B = 8, T = 4096, D = 1024, H = 16;
    const int M = B * T;                       // 32768
    const float scale = 0.35355339059327379f;  // 64^-0.25

    float* phiq  = (float*)d_ws;               // M*D fp32
    float* phik  = phiq + (size_t)M * D;       // M*D fp32 (later reused as Oattn)
    float* vbuf  = phik + (size_t)M * D;       // M*D fp32
    float* kvbuf = vbuf + (size_t)M * D;       // B*H*64*64 fp32
    (void)ws_size; (void)in_sizes; (void)n_in; (void)out_size;

    dim3 blk(256);

    // q/k/v projections + phi fused epilogue
    qkv_gemm<<<dim3(D / TILE, M / TILE, 3), blk, 0, stream>>>(
        x, Wq, bq, Wk, Wv, bv, phiq, phik, vbuf, M, D, D, scale);

    // kv = phi_k^T v   per (b,h)
    kv_kernel<<<dim3(B * H), blk, 0, stream>>>(phik, vbuf, kvbuf, T, D);

    // out = phi_q @ kv  (write into phik's buffer, no longer needed)
    av_kernel<<<dim3(T / 64, B * H), blk, 0, stream>>>(phiq, kvbuf, phik, T, D);

    // final projection
    out_gemm<<<dim3(D / TILE, M / TILE), blk, 0, stream>>>(phik, Wo, bo, out, M, D, D);
}

// Round 2
// 912.864 us; speedup vs baseline: 4.9950x; 4.9950x over previous
//
#include <hip/hip_runtime.h>
#include <math.h>

typedef short bf16x8 __attribute__((ext_vector_type(8)));
typedef float f32x4  __attribute__((ext_vector_type(4)));

__device__ __forceinline__ float phi_act(float t) {
    return t / (1.0f + __expf(-t)) + 1.0f;   // silu(t)+1
}

__device__ __forceinline__ unsigned short f2bf(float f) {
    union { float f; unsigned int u; } un; un.f = f;
    unsigned int r = un.u + 0x7fffu + ((un.u >> 16) & 1u);  // RNE
    return (unsigned short)(r >> 16);
}

__device__ __forceinline__ void gload_lds16(const void* g, void* l) {
    __builtin_amdgcn_global_load_lds(
        (const __attribute__((address_space(1))) void*)g,
        (__attribute__((address_space(3))) void*)l, 16, 0, 0);
}

// C[M,N] = A[M,K](bf16) @ W[N,K](bf16)^T, fp32 accum.
// mode 0: fp32 store of acc + bias
// mode 1: bf16 store of phi((acc + bias) * scale)   (bias may be null)
// mode 2: bf16 store of acc + bias
__device__ __forceinline__ void gemm_body_mfma(
    const unsigned short* __restrict__ A, const unsigned short* __restrict__ W,
    const float* __restrict__ bias, float* __restrict__ outF,
    unsigned short* __restrict__ outB,
    int N, int K, int mode, float scale)
{
    __shared__ unsigned short As[128 * 32];   // [row][k] row-major, 64B rows, NO pad
    __shared__ unsigned short Bs[128 * 32];

    const int tid  = threadIdx.x;
    const int lane = tid & 63;
    const int w    = tid >> 6;          // wave 0..3
    const int wm   = w >> 1, wn = w & 1;
    const int bm   = blockIdx.y, bn = blockIdx.x;

    // staging geometry: 8KB per tile = 8 chunks of 1KB; wave w owns chunks w*2, w*2+1.
    // chunk c covers rows c*16 .. c*16+15 (row = 32 bf16 = 64B); lane l -> row c*16 + l/4, kcol (l%4)*8
    const int lrow = lane >> 2;
    const int kcol = (lane & 3) * 8;
    const int c0   = w * 2;

    const size_t arow0 = (size_t)(bm * 128);
    const size_t brow0 = (size_t)(bn * 128);

    f32x4 zero4 = {0.f, 0.f, 0.f, 0.f};
    f32x4 acc[4][4];
    #pragma unroll
    for (int i = 0; i < 4; i++)
        #pragma unroll
        for (int j = 0; j < 4; j++) acc[i][j] = zero4;

    const int kq = lane >> 4;      // 0..3
    const int ml = lane & 15;

    for (int k0 = 0; k0 < K; k0 += 32) {
        __syncthreads();
        #pragma unroll
        for (int u = 0; u < 2; u++) {
            const int c = c0 + u;
            const int row = c * 16 + lrow;
            gload_lds16(A + (arow0 + row) * K + k0 + kcol, &As[c * 512]);
            gload_lds16(W + (brow0 + row) * K + k0 + kcol, &Bs[c * 512]);
        }
        __syncthreads();

        bf16x8 af[4], bfr[4];
        #pragma unroll
        for (int mi = 0; mi < 4; mi++)
            af[mi] = *(const bf16x8*)&As[(wm * 64 + mi * 16 + ml) * 32 + kq * 8];
        #pragma unroll
        for (int nj = 0; nj < 4; nj++)
            bfr[nj] = *(const bf16x8*)&Bs[(wn * 64 + nj * 16 + ml) * 32 + kq * 8];

        #pragma unroll
        for (int mi = 0; mi < 4; mi++)
            #pragma unroll
            for (int nj = 0; nj < 4; nj++)
                acc[mi][nj] = __builtin_amdgcn_mfma_f32_16x16x32_bf16(
                    af[mi], bfr[nj], acc[mi][nj], 0, 0, 0);
    }

    // epilogue: C/D layout col=lane&15, row=(lane>>4)*4+reg
    const int rq = (lane >> 4) * 2;  // *4 later; avoid shadow
    const int cl = lane & 15;
    #pragma unroll
    for (int nj = 0; nj < 4; nj++) {
        const int col = bn * 128 + wn * 64 + nj * 16 + cl;
        const float bv = bias ? bias[col] : 0.f;
        #pragma unroll
        for (int mi = 0; mi < 4; mi++) {
            const int rowb = bm * 128 + wm * 64 + mi * 16 + rq * 2;
            #pragma unroll
            for (int r = 0; r < 4; r++) {
                float v = acc[mi][nj][r] + bv;
                const size_t idx = (size_t)(rowb + r) * N + col;
                if (mode == 0) {
                    outF[idx] = v;
                } else {
                    if (mode == 1) v = phi_act(v * scale);
                    outB[idx] = f2bf(v);
                }
            }
        }
    }
}

__global__ __launch_bounds__(256) void qkv_gemm_mfma(
    const unsigned short* __restrict__ xb,
    const unsigned short* __restrict__ wqb, const float* __restrict__ bq,
    const unsigned short* __restrict__ wkb,
    const unsigned short* __restrict__ wvb, const float* __restrict__ bv,
    unsigned short* __restrict__ phiq, unsigned short* __restrict__ phik,
    unsigned short* __restrict__ vb,
    int N, int K, float scale)
{
    const int z = blockIdx.z;
    if (z == 0)      gemm_body_mfma(xb, wqb, bq,      nullptr, phiq, N, K, 1, scale);
    else if (z == 1) gemm_body_mfma(xb, wkb, nullptr, nullptr, phik, N, K, 1, scale);
    else             gemm_body_mfma(xb, wvb, bv,      nullptr, vb,   N, K, 2, 1.0f);
}

__global__ __launch_bounds__(256) void out_gemm_mfma(
    const unsigned short* __restrict__ A, const unsigned short* __restrict__ W,
    const float* __restrict__ bias, float* __restrict__ C, int N, int K)
{
    gemm_body_mfma(A, W, bias, C, nullptr, N, K, 0, 1.0f);
}

// fused fp32 -> bf16 cast for x + 4 weight matrices
__global__ __launch_bounds__(256) void cast_all(
    const float* __restrict__ x,  unsigned short* __restrict__ xb,
    const float* __restrict__ w0, unsigned short* __restrict__ w0b,
    const float* __restrict__ w1, unsigned short* __restrict__ w1b,
    const float* __restrict__ w2, unsigned short* __restrict__ w2b,
    const float* __restrict__ w3, unsigned short* __restrict__ w3b,
    size_t nx, size_t nw)
{
    size_t i = ((size_t)blockIdx.x * 256 + threadIdx.x) * 4;
    const float* s; unsigned short* d; size_t off;
    if (i < nx)               { s = x;  d = xb;  off = i; }
    else if (i < nx + nw)     { s = w0; d = w0b; off = i - nx; }
    else if (i < nx + 2 * nw) { s = w1; d = w1b; off = i - nx - nw; }
    else if (i < nx + 3 * nw) { s = w2; d = w2b; off = i - nx - 2 * nw; }
    else                      { s = w3; d = w3b; off = i - nx - 3 * nw; }
    float4 v = *(const float4*)(s + off);
    ushort4 o;
    o.x = f2bf(v.x); o.y = f2bf(v.y); o.z = f2bf(v.z); o.w = f2bf(v.w);
    *(ushort4*)(d + off) = o;
}

__device__ __forceinline__ void bf8_store(float* dst, uint4 u) {
    dst[0] = __uint_as_float(u.x << 16); dst[1] = __uint_as_float(u.x & 0xffff0000u);
    dst[2] = __uint_as_float(u.y << 16); dst[3] = __uint_as_float(u.y & 0xffff0000u);
    dst[4] = __uint_as_float(u.z << 16); dst[5] = __uint_as_float(u.z & 0xffff0000u);
    dst[6] = __uint_as_float(u.w << 16); dst[7] = __uint_as_float(u.w & 0xffff0000u);
}

// kv[bh][d][e] = sum_t phiK[b,t,h*64+d] * V[b,t,h*64+e]   (bf16 in, fp32 out)
__global__ __launch_bounds__(256) void kv_kernel(
    const unsigned short* __restrict__ phiK, const unsigned short* __restrict__ V,
    float* __restrict__ KV, int Ttot, int D)
{
    const int bh = blockIdx.x;
    const int b = bh >> 4, h = bh & 15;
    __shared__ float pk[32][64];
    __shared__ float vv[32][64];
    const int tid = threadIdx.x;
    const int tx = tid & 15, ty = tid >> 4;
    const int e0 = tx << 2, d0 = ty << 2;
    float acc[4][4] = {};
    const size_t base = (size_t)b * Ttot * D + h * 64;
    const int r = tid >> 3, c8 = (tid & 7) << 3;

    for (int t0 = 0; t0 < Ttot; t0 += 32) {
        const size_t g = base + (size_t)(t0 + r) * D + c8;
        uint4 ku = *(const uint4*)(phiK + g);
        uint4 vu = *(const uint4*)(V + g);
        __syncthreads();
        bf8_store(&pk[r][c8], ku);
        bf8_store(&vv[r][c8], vu);
        __syncthreads();
        #pragma unroll
        for (int tt = 0; tt < 32; tt++) {
            float4 a = *(const float4*)&pk[tt][d0];
            float4 wv = *(const float4*)&vv[tt][e0];
            acc[0][0] += a.x * wv.x; acc[0][1] += a.x * wv.y; acc[0][2] += a.x * wv.z; acc[0][3] += a.x * wv.w;
            acc[1][0] += a.y * wv.x; acc[1][1] += a.y * wv.y; acc[1][2] += a.y * wv.z; acc[1][3] += a.y * wv.w;
            acc[2][0] += a.z * wv.x; acc[2][1] += a.z * wv.y; acc[2][2] += a.z * wv.z; acc[2][3] += a.z * wv.w;
            acc[3][0] += a.w * wv.x; acc[3][1] += a.w * wv.y; acc[3][2] += a.w * wv.z; acc[3][3] += a.w * wv.w;
        }
    }
    float* outp = KV + (size_t)bh * 4096;
    #pragma unroll
    for (int i = 0; i < 4; i++)
        *(float4*)&outp[(d0 + i) * 64 + e0] =
            make_float4(acc[i][0], acc[i][1], acc[i][2], acc[i][3]);
}

// Oattn[b,t,h*64+e] = sum_d phiQ[b,t,h*64+d] * kv[bh][d][e]  (bf16 in/out, fp32 kv)
__global__ __launch_bounds__(256) void av_kernel(
    const unsigned short* __restrict__ phiQ, const float* __restrict__ KV,
    unsigned short* __restrict__ Oattn, int Ttot, int D)
{
    const int bh = blockIdx.y;
    const int b = bh >> 4, h = bh & 15;
    const int t0 = blockIdx.x * 64;
    __shared__ float kvs[64][64];
    __shared__ float pqT[64][64 + 4];
    const int tid = threadIdx.x;
    const int tx = tid & 15, ty = tid >> 4;

    const float* kvp = KV + (size_t)bh * 4096;
    #pragma unroll
    for (int u = 0; u < 4; u++) {
        int f = tid + u * 256;
        int rr = f >> 4;
        int c4 = (f & 15) << 2;
        *(float4*)&kvs[rr][c4] = *(const float4*)(kvp + f * 4);
    }
    #pragma unroll
    for (int u = 0; u < 2; u++) {
        int f = tid * 2 + u;               // 0..511
        int rr = f >> 3;                   // 0..63
        int c8 = (f & 7) << 3;             // 0..56
        uint4 g = *(const uint4*)(phiQ + (size_t)(b * Ttot + t0 + rr) * D + h * 64 + c8);
        pqT[c8 + 0][rr] = __uint_as_float(g.x << 16);
        pqT[c8 + 1][rr] = __uint_as_float(g.x & 0xffff0000u);
        pqT[c8 + 2][rr] = __uint_as_float(g.y << 16);
        pqT[c8 + 3][rr] = __uint_as_float(g.y & 0xffff0000u);
        pqT[c8 + 4][rr] = __uint_as_float(g.z << 16);
        pqT[c8 + 5][rr] = __uint_as_float(g.z & 0xffff0000u);
        pqT[c8 + 6][rr] = __uint_as_float(g.w << 16);
        pqT[c8 + 7][rr] = __uint_as_float(g.w & 0xffff0000u);
    }
    __syncthreads();

    const int e0 = tx << 2, tl0 = ty << 2;
    float acc[4][4] = {};
    #pragma unroll 8
    for (int d = 0; d < 64; d++) {
        float4 a = *(const float4*)&pqT[d][tl0];
        float4 wv = *(const float4*)&kvs[d][e0];
        acc[0][0] += a.x * wv.x; acc[0][1] += a.x * wv.y; acc[0][2] += a.x * wv.z; acc[0][3] += a.x * wv.w;
        acc[1][0] += a.y * wv.x; acc[1][1] += a.y * wv.y; acc[1][2] += a.y * wv.z; acc[1][3] += a.y * wv.w;
        acc[2][0] += a.z * wv.x; acc[2][1] += a.z * wv.y; acc[2][2] += a.z * wv.z; acc[2][3] += a.z * wv.w;
        acc[3][0] += a.w * wv.x; acc[3][1] += a.w * wv.y; acc[3][2] += a.w * wv.z; acc[3][3] += a.w * wv.w;
    }
    #pragma unroll
    for (int i = 0; i < 4; i++) {
        ushort4 o;
        o.x = f2bf(acc[i][0]); o.y = f2bf(acc[i][1]);
        o.z = f2bf(acc[i][2]); o.w = f2bf(acc[i][3]);
        *(ushort4*)&Oattn[(size_t)(b * Ttot + t0 + tl0 + i) * D + h * 64 + e0] = o;
    }
}

extern "C" void kernel_launch(void* const* d_in, const int* in_sizes, int n_in,
                              void* d_out, int out_size, void* d_ws, size_t ws_size,
                              hipStream_t stream) {
    const float* x  = (const float*)d_in[0];
    const float* Wq = (const float*)d_in[1];
    const float* bq = (const float*)d_in[2];
    const float* Wk = (const float*)d_in[3];
    const float* Wv = (const float*)d_in[4];
    const float* bv = (const float*)d_in[5];
    const float* Wo = (const float*)d_in[6];
    const float* bo = (const float*)d_in[7];
    float* out = (float*)d_out;

    const int B = 8, T = 4096, D = 1024;
    const int M = B * T;                       // 32768
    const float scale = 0.35355339059327379f;  // 64^-0.25
    const size_t MD = (size_t)M * D;
    const size_t WN = (size_t)D * D;

    unsigned short* xb    = (unsigned short*)d_ws;
    unsigned short* wqb   = xb + MD;
    unsigned short* wkb   = wqb + WN;
    unsigned short* wvb   = wkb + WN;
    unsigned short* wob   = wvb + WN;
    unsigned short* phiq  = wob + WN;
    unsigned short* phik  = phiq + MD;
    unsigned short* vb    = phik + MD;
    unsigned short* oat   = vb + MD;
    float*          kvbuf = (float*)(oat + MD);    // B*H*64*64 fp32 = 2 MB
    (void)ws_size; (void)in_sizes; (void)n_in; (void)out_size;

    dim3 blk(256);

    // 1) cast x + weights to bf16
    {
        size_t total4 = (MD + 4 * WN) / 4;
        cast_all<<<dim3((unsigned)(total4 / 256)), blk, 0, stream>>>(
            x, xb, Wq, wqb, Wk, wkb, Wv, wvb, Wo, wob, MD, WN);
    }

    // 2) q/k/v projections (phi fused for q,k)
    qkv_gemm_mfma<<<dim3(D / 128, M / 128, 3), blk, 0, stream>>>(
        xb, wqb, bq, wkb, wvb, bv, phiq, phik, vb, D, D, scale);

    // 3) kv = phi_k^T v per (b,h)
    kv_kernel<<<dim3(128), blk, 0, stream>>>(phik, vb, kvbuf, T, D);

    // 4) Oattn = phi_q @ kv
    av_kernel<<<dim3(T / 64, 128), blk, 0, stream>>>(phiq, kvbuf, oat, T, D);

    // 5) final projection (fp32 out + bias)
    out_gemm_mfma<<<dim3(D / 128, M / 128), blk, 0, stream>>>(oat, wob, bo, out, D, D);
}

// Round 3
// 713.375 us; speedup vs baseline: 6.3918x; 1.2796x over previous
//
#include <hip/hip_runtime.h>
#include <math.h>

typedef short bf16x8 __attribute__((ext_vector_type(8)));
typedef float f32x4  __attribute__((ext_vector_type(4)));

__device__ __forceinline__ float phi_act(float t) {
    return t / (1.0f + __expf(-t)) + 1.0f;   // silu(t)+1
}

__device__ __forceinline__ unsigned short f2bf(float f) {
    union { float f; unsigned int u; } un; un.f = f;
    unsigned int r = un.u + 0x7fffu + ((un.u >> 16) & 1u);  // RNE
    return (unsigned short)(r >> 16);
}

__device__ __forceinline__ void gload_lds16(const void* g, void* l) {
    __builtin_amdgcn_global_load_lds(
        (const __attribute__((address_space(1))) void*)g,
        (__attribute__((address_space(3))) void*)l, 16, 0, 0);
}

// ---------------- big GEMMs (m97 structure, unchanged from R2) ----------------
// C[M,N] = A[M,K](bf16) @ W[N,K](bf16)^T, fp32 accum.
// mode 0: fp32 store of acc + bias
// mode 1: bf16 store of phi((acc + bias) * scale)   (bias may be null)
// mode 2: bf16 store of acc + bias
__device__ __forceinline__ void gemm_body_mfma(
    const unsigned short* __restrict__ A, const unsigned short* __restrict__ W,
    const float* __restrict__ bias, float* __restrict__ outF,
    unsigned short* __restrict__ outB,
    int N, int K, int mode, float scale)
{
    __shared__ unsigned short As[128 * 32];   // [row][k], 64B rows, NO pad (global_load_lds)
    __shared__ unsigned short Bs[128 * 32];

    const int tid  = threadIdx.x;
    const int lane = tid & 63;
    const int w    = tid >> 6;
    const int wm   = w >> 1, wn = w & 1;
    const int bm   = blockIdx.y, bn = blockIdx.x;

    const int lrow = lane >> 2;
    const int kcol = (lane & 3) * 8;
    const int c0   = w * 2;

    const size_t arow0 = (size_t)(bm * 128);
    const size_t brow0 = (size_t)(bn * 128);

    f32x4 zero4 = {0.f, 0.f, 0.f, 0.f};
    f32x4 acc[4][4];
    #pragma unroll
    for (int i = 0; i < 4; i++)
        #pragma unroll
        for (int j = 0; j < 4; j++) acc[i][j] = zero4;

    const int kq = lane >> 4;
    const int ml = lane & 15;

    for (int k0 = 0; k0 < K; k0 += 32) {
        __syncthreads();
        #pragma unroll
        for (int u = 0; u < 2; u++) {
            const int c = c0 + u;
            const int row = c * 16 + lrow;
            gload_lds16(A + (arow0 + row) * K + k0 + kcol, &As[c * 512]);
            gload_lds16(W + (brow0 + row) * K + k0 + kcol, &Bs[c * 512]);
        }
        __syncthreads();

        bf16x8 af[4], bfr[4];
        #pragma unroll
        for (int mi = 0; mi < 4; mi++)
            af[mi] = *(const bf16x8*)&As[(wm * 64 + mi * 16 + ml) * 32 + kq * 8];
        #pragma unroll
        for (int nj = 0; nj < 4; nj++)
            bfr[nj] = *(const bf16x8*)&Bs[(wn * 64 + nj * 16 + ml) * 32 + kq * 8];

        #pragma unroll
        for (int mi = 0; mi < 4; mi++)
            #pragma unroll
            for (int nj = 0; nj < 4; nj++)
                acc[mi][nj] = __builtin_amdgcn_mfma_f32_16x16x32_bf16(
                    af[mi], bfr[nj], acc[mi][nj], 0, 0, 0);
    }

    const int rq = lane >> 4;
    const int cl = lane & 15;
    #pragma unroll
    for (int nj = 0; nj < 4; nj++) {
        const int col = bn * 128 + wn * 64 + nj * 16 + cl;
        const float bvv = bias ? bias[col] : 0.f;
        #pragma unroll
        for (int mi = 0; mi < 4; mi++) {
            const int rowb = bm * 128 + wm * 64 + mi * 16 + rq * 4;
            #pragma unroll
            for (int r = 0; r < 4; r++) {
                float v = acc[mi][nj][r] + bvv;
                const size_t idx = (size_t)(rowb + r) * N + col;
                if (mode == 0) {
                    outF[idx] = v;
                } else {
                    if (mode == 1) v = phi_act(v * scale);
                    outB[idx] = f2bf(v);
                }
            }
        }
    }
}

__global__ __launch_bounds__(256) void qkv_gemm_mfma(
    const unsigned short* __restrict__ xb,
    const unsigned short* __restrict__ wqb, const float* __restrict__ bq,
    const unsigned short* __restrict__ wkb,
    const unsigned short* __restrict__ wvb, const float* __restrict__ bv,
    unsigned short* __restrict__ phiq, unsigned short* __restrict__ phik,
    unsigned short* __restrict__ vb,
    int N, int K, float scale)
{
    const int z = blockIdx.z;
    if (z == 0)      gemm_body_mfma(xb, wqb, bq,      nullptr, phiq, N, K, 1, scale);
    else if (z == 1) gemm_body_mfma(xb, wkb, nullptr, nullptr, phik, N, K, 1, scale);
    else             gemm_body_mfma(xb, wvb, bv,      nullptr, vb,   N, K, 2, 1.0f);
}

__global__ __launch_bounds__(256) void out_gemm_mfma(
    const unsigned short* __restrict__ A, const unsigned short* __restrict__ W,
    const float* __restrict__ bias, float* __restrict__ C, int N, int K)
{
    gemm_body_mfma(A, W, bias, C, nullptr, N, K, 0, 1.0f);
}

// ---------------- cast ----------------
__global__ __launch_bounds__(256) void cast_all(
    const float* __restrict__ x,  unsigned short* __restrict__ xb,
    const float* __restrict__ w0, unsigned short* __restrict__ w0b,
    const float* __restrict__ w1, unsigned short* __restrict__ w1b,
    const float* __restrict__ w2, unsigned short* __restrict__ w2b,
    const float* __restrict__ w3, unsigned short* __restrict__ w3b,
    size_t nx, size_t nw)
{
    size_t i = ((size_t)blockIdx.x * 256 + threadIdx.x) * 4;
    const float* s; unsigned short* d; size_t off;
    if (i < nx)               { s = x;  d = xb;  off = i; }
    else if (i < nx + nw)     { s = w0; d = w0b; off = i - nx; }
    else if (i < nx + 2 * nw) { s = w1; d = w1b; off = i - nx - nw; }
    else if (i < nx + 3 * nw) { s = w2; d = w2b; off = i - nx - 2 * nw; }
    else                      { s = w3; d = w3b; off = i - nx - 3 * nw; }
    float4 v = *(const float4*)(s + off);
    ushort4 o;
    o.x = f2bf(v.x); o.y = f2bf(v.y); o.z = f2bf(v.z); o.w = f2bf(v.w);
    *(ushort4*)(d + off) = o;
}

// ---------------- kv = phi_k^T v : MFMA split-T partials ----------------
// grid (tc=8, bh=128). partial[(bh*8+tc)][d*64+e] fp32.
__global__ __launch_bounds__(256) void kv_part(
    const unsigned short* __restrict__ phiK, const unsigned short* __restrict__ V,
    float* __restrict__ partial, int Ttot, int D)
{
    const int tc = blockIdx.x, bh = blockIdx.y;
    const int b = bh >> 4, h = bh & 15;
    const int tbase = tc * 512;

    __shared__ unsigned short pkT[64][72];   // [d][t], +8 pad
    __shared__ unsigned short vvT[64][72];   // [e][t]

    const int tid  = threadIdx.x;
    const int lane = tid & 63;
    const int w    = tid >> 6;
    const int dq = w >> 1, eq = w & 1;
    const int kq = lane >> 4, ml = lane & 15;

    f32x4 zero4 = {0.f, 0.f, 0.f, 0.f};
    f32x4 acc[2][2];
    acc[0][0] = zero4; acc[0][1] = zero4; acc[1][0] = zero4; acc[1][1] = zero4;

    const size_t base = (size_t)b * Ttot * D + h * 64;

    for (int c8 = 0; c8 < 8; c8++) {
        const int t0 = tbase + c8 * 64;
        __syncthreads();
        #pragma unroll
        for (int u = 0; u < 2; u++) {
            const int f = tid * 2 + u;          // 0..511
            const int trow = f >> 3;            // 0..63
            const int d8 = (f & 7) * 8;         // 0..56
            const size_t g = base + (size_t)(t0 + trow) * D + d8;
            uint4 kk = *(const uint4*)(phiK + g);
            uint4 vv = *(const uint4*)(V + g);
            pkT[d8 + 0][trow] = (unsigned short)(kk.x & 0xffff);
            pkT[d8 + 1][trow] = (unsigned short)(kk.x >> 16);
            pkT[d8 + 2][trow] = (unsigned short)(kk.y & 0xffff);
            pkT[d8 + 3][trow] = (unsigned short)(kk.y >> 16);
            pkT[d8 + 4][trow] = (unsigned short)(kk.z & 0xffff);
            pkT[d8 + 5][trow] = (unsigned short)(kk.z >> 16);
            pkT[d8 + 6][trow] = (unsigned short)(kk.w & 0xffff);
            pkT[d8 + 7][trow] = (unsigned short)(kk.w >> 16);
            vvT[d8 + 0][trow] = (unsigned short)(vv.x & 0xffff);
            vvT[d8 + 1][trow] = (unsigned short)(vv.x >> 16);
            vvT[d8 + 2][trow] = (unsigned short)(vv.y & 0xffff);
            vvT[d8 + 3][trow] = (unsigned short)(vv.y >> 16);
            vvT[d8 + 4][trow] = (unsigned short)(vv.z & 0xffff);
            vvT[d8 + 5][trow] = (unsigned short)(vv.z >> 16);
            vvT[d8 + 6][trow] = (unsigned short)(vv.w & 0xffff);
            vvT[d8 + 7][trow] = (unsigned short)(vv.w >> 16);
        }
        __syncthreads();

        #pragma unroll
        for (int ks = 0; ks < 2; ks++) {
            bf16x8 af[2], bfv[2];
            #pragma unroll
            for (int ai = 0; ai < 2; ai++)
                af[ai] = *(const bf16x8*)&pkT[dq * 32 + ai * 16 + ml][ks * 32 + kq * 8];
            #pragma unroll
            for (int bi = 0; bi < 2; bi++)
                bfv[bi] = *(const bf16x8*)&vvT[eq * 32 + bi * 16 + ml][ks * 32 + kq * 8];
            #pragma unroll
            for (int ai = 0; ai < 2; ai++)
                #pragma unroll
                for (int bi = 0; bi < 2; bi++)
                    acc[ai][bi] = __builtin_amdgcn_mfma_f32_16x16x32_bf16(
                        af[ai], bfv[bi], acc[ai][bi], 0, 0, 0);
        }
    }

    float* outp = partial + ((size_t)bh * 8 + tc) * 4096;
    const int rq = lane >> 4, cl = lane & 15;
    #pragma unroll
    for (int ai = 0; ai < 2; ai++)
        #pragma unroll
        for (int bi = 0; bi < 2; bi++) {
            const int e = eq * 32 + bi * 16 + cl;
            #pragma unroll
            for (int r = 0; r < 4; r++) {
                const int d = dq * 32 + ai * 16 + rq * 4 + r;
                outp[d * 64 + e] = acc[ai][bi][r];
            }
        }
}

// reduce 8 partials -> kvT bf16 [bh][e*64+d]
__global__ __launch_bounds__(256) void kv_reduce(
    const float* __restrict__ partial, unsigned short* __restrict__ kvT)
{
    const int bh = blockIdx.x;
    const int tid = threadIdx.x;
    __shared__ float s[64][65];
    float a[16];
    #pragma unroll
    for (int c = 0; c < 16; c++) a[c] = 0.f;
    #pragma unroll
    for (int p = 0; p < 8; p++) {
        const float* src = partial + ((size_t)bh * 8 + p) * 4096;
        #pragma unroll
        for (int c = 0; c < 16; c++) a[c] += src[c * 256 + tid];
    }
    #pragma unroll
    for (int c = 0; c < 16; c++) {
        const int idx = c * 256 + tid;       // d*64+e
        s[idx >> 6][idx & 63] = a[c];
    }
    __syncthreads();
    unsigned short* outp = kvT + (size_t)bh * 4096;
    #pragma unroll
    for (int c = 0; c < 16; c++) {
        const int j = c * 256 + tid;         // e*64+d
        outp[j] = f2bf(s[j & 63][j >> 6]);
    }
}

// ---------------- Oattn = phi_q @ kv : MFMA ----------------
// grid (T/256, bh). A = phiq [t][d], B = kvT [e][d].
__global__ __launch_bounds__(256) void av_mfma(
    const unsigned short* __restrict__ phiQ, const unsigned short* __restrict__ kvT,
    unsigned short* __restrict__ Oattn, int Ttot, int D)
{
    const int bh = blockIdx.y;
    const int b = bh >> 4, h = bh & 15;
    const int t0 = blockIdx.x * 256;

    __shared__ unsigned short Aq[256 * 64];  // [t][d], 128B rows (global_load_lds)
    __shared__ unsigned short Kv[64][72];    // [e][d], +8 pad

    const int tid  = threadIdx.x;
    const int lane = tid & 63;
    const int w    = tid >> 6;
    const int kq = lane >> 4, ml = lane & 15;

    // stage Kv: each thread copies 16 elements (2x 16B)
    {
        const int e = tid >> 2;              // 0..63
        const int c16 = (tid & 3) * 16;      // 0,16,32,48
        const unsigned short* src = kvT + (size_t)bh * 4096 + e * 64 + c16;
        *(uint4*)&Kv[e][c16]     = *(const uint4*)(src);
        *(uint4*)&Kv[e][c16 + 8] = *(const uint4*)(src + 8);
    }
    // stage Aq via global_load_lds: 32 KB = 8 rounds x 4 waves x 1KB
    {
        const int lr = lane >> 3;            // 0..7
        const int d8 = (lane & 7) * 8;       // 0..56
        #pragma unroll
        for (int r = 0; r < 8; r++) {
            const int chunk = r * 4 + w;     // 0..31, 8 rows each
            const int row = chunk * 8 + lr;  // t within tile
            gload_lds16(phiQ + ((size_t)(b * Ttot + t0 + row)) * D + h * 64 + d8,
                        &Aq[chunk * 512]);
        }
    }
    __syncthreads();

    f32x4 zero4 = {0.f, 0.f, 0.f, 0.f};
    f32x4 acc[4][4];
    #pragma unroll
    for (int i = 0; i < 4; i++)
        #pragma unroll
        for (int j = 0; j < 4; j++) acc[i][j] = zero4;

    #pragma unroll
    for (int ks = 0; ks < 2; ks++) {
        bf16x8 af[4], bfv[4];
        #pragma unroll
        for (int mi = 0; mi < 4; mi++)
            af[mi] = *(const bf16x8*)&Aq[(w * 64 + mi * 16 + ml) * 64 + ks * 32 + kq * 8];
        #pragma unroll
        for (int nj = 0; nj < 4; nj++)
            bfv[nj] = *(const bf16x8*)&Kv[nj * 16 + ml][ks * 32 + kq * 8];
        #pragma unroll
        for (int mi = 0; mi < 4; mi++)
            #pragma unroll
            for (int nj = 0; nj < 4; nj++)
                acc[mi][nj] = __builtin_amdgcn_mfma_f32_16x16x32_bf16(
                    af[mi], bfv[nj], acc[mi][nj], 0, 0, 0);
    }

    const int rq = lane >> 4, cl = lane & 15;
    #pragma unroll
    for (int mi = 0; mi < 4; mi++) {
        #pragma unroll
        for (int r = 0; r < 4; r++) {
            const int t = t0 + w * 64 + mi * 16 + rq * 4 + r;
            unsigned short* dst = Oattn + (size_t)(b * Ttot + t) * D + h * 64;
            #pragma unroll
            for (int nj = 0; nj < 4; nj++)
                dst[nj * 16 + cl] = f2bf(acc[mi][nj][r]);
        }
    }
}

extern "C" void kernel_launch(void* const* d_in, const int* in_sizes, int n_in,
                              void* d_out, int out_size, void* d_ws, size_t ws_size,
                              hipStream_t stream) {
    const float* x  = (const float*)d_in[0];
    const float* Wq = (const float*)d_in[1];
    const float* bq = (const float*)d_in[2];
    const float* Wk = (const float*)d_in[3];
    const float* Wv = (const float*)d_in[4];
    const float* bv = (const float*)d_in[5];
    const float* Wo = (const float*)d_in[6];
    const float* bo = (const float*)d_in[7];
    float* out = (float*)d_out;

    const int B = 8, T = 4096, D = 1024;
    const int M = B * T;                       // 32768
    const float scale = 0.35355339059327379f;  // 64^-0.25
    const size_t MD = (size_t)M * D;
    const size_t WN = (size_t)D * D;

    unsigned short* xb    = (unsigned short*)d_ws;
    unsigned short* wqb   = xb + MD;
    unsigned short* wkb   = wqb + WN;
    unsigned short* wvb   = wkb + WN;
    unsigned short* wob   = wvb + WN;
    unsigned short* phiq  = wob + WN;
    unsigned short* phik  = phiq + MD;
    unsigned short* vb    = phik + MD;
    unsigned short* oat   = vb + MD;
    float*          part  = (float*)(oat + MD);         // 1024*4096 fp32 = 16 MB
    unsigned short* kvT   = (unsigned short*)(part + (size_t)1024 * 4096); // 1 MB
    (void)ws_size; (void)in_sizes; (void)n_in; (void)out_size;

    dim3 blk(256);

    // 1) cast x + weights to bf16
    {
        size_t total4 = (MD + 4 * WN) / 4;
        cast_all<<<dim3((unsigned)(total4 / 256)), blk, 0, stream>>>(
            x, xb, Wq, wqb, Wk, wkb, Wv, wvb, Wo, wob, MD, WN);
    }

    // 2) q/k/v projections (phi fused for q,k)
    qkv_gemm_mfma<<<dim3(D / 128, M / 128, 3), blk, 0, stream>>>(
        xb, wqb, bq, wkb, wvb, bv, phiq, phik, vb, D, D, scale);

    // 3) kv partials + reduce (-> kvT bf16)
    kv_part<<<dim3(8, 128), blk, 0, stream>>>(phik, vb, part, T, D);
    kv_reduce<<<dim3(128), blk, 0, stream>>>(part, kvT);

    // 4) Oattn = phi_q @ kv
    av_mfma<<<dim3(T / 256, 128), blk, 0, stream>>>(phiq, kvT, oat, T, D);

    // 5) final projection (fp32 out + bias)
    out_gemm_mfma<<<dim3(D / 128, M / 128), blk, 0, stream>>>(oat, wob, bo, out, D, D);
}